// Round 1
// baseline (370.616 us; speedup 1.0000x reference)
//
#include <hip/hip_runtime.h>
#include <hip/hip_bf16.h>
#include <math.h>

#define CH 128          // IN_CH == OUT_CH == 128
#define NEG_SLOPE 0.2f
#define LN_EPS 1e-5f

// ---------------------------------------------------------------------------
// K1: xl = x@W_l + b_l ; xr = x@W_r + b_r   (fp32 vector ALU, LDS-staged x)
// block = 256 threads, 8 nodes/block
// ---------------------------------------------------------------------------
__global__ __launch_bounds__(256) void k_transform(
    const float* __restrict__ x,
    const float* __restrict__ Wl, const float* __restrict__ bl,
    const float* __restrict__ Wr, const float* __restrict__ br,
    float* __restrict__ xl, float* __restrict__ xr, int N)
{
    __shared__ float xs[8][CH];
    const int nb = blockIdx.x * 8;
    const int t  = threadIdx.x;

    // stage 8 rows of x (8*128 floats) with 256 float4 loads
    {
        int idx = t * 4;            // 0..1023
        int r   = idx >> 7;         // row 0..7
        int kk  = idx & 127;
        int n   = nb + r;
        float4 v = make_float4(0.f, 0.f, 0.f, 0.f);
        if (n < N) v = *(const float4*)&x[(size_t)n * CH + kk];
        *(float4*)&xs[r][kk] = v;
    }
    __syncthreads();

    const int c    = t & 127;       // output channel
    const int half = t >> 7;        // 0 or 1 -> nodes {4h..4h+3}
    float accl[4] = {0.f, 0.f, 0.f, 0.f};
    float accr[4] = {0.f, 0.f, 0.f, 0.f};

#pragma unroll 4
    for (int k = 0; k < CH; ++k) {
        float wl = Wl[k * CH + c];
        float wr = Wr[k * CH + c];
#pragma unroll
        for (int i = 0; i < 4; ++i) {
            float xv = xs[half * 4 + i][k];   // LDS broadcast
            accl[i] += xv * wl;
            accr[i] += xv * wr;
        }
    }

    const float bbl = bl[c], bbr = br[c];
#pragma unroll
    for (int i = 0; i < 4; ++i) {
        int n = nb + half * 4 + i;
        if (n < N) {
            xl[(size_t)n * CH + c] = accl[i] + bbl;
            xr[(size_t)n * CH + c] = accr[i] + bbr;
        }
    }
}

// ---------------------------------------------------------------------------
// CSR build: deg init (self-loop=1) -> count -> 2-level scan -> cursor -> fill
// ---------------------------------------------------------------------------
__global__ void k_deg_init(int* __restrict__ deg, int N)
{
    int i = blockIdx.x * 256 + threadIdx.x;
    if (i < N) deg[i] = 1;   // self-loop
}

__global__ void k_count(const int* __restrict__ ei, int E, int* __restrict__ deg)
{
    int e = blockIdx.x * 256 + threadIdx.x;
    if (e < E) {
        int d = ei[E + e];   // row 1 = dst
        atomicAdd(&deg[d], 1);
    }
}

__global__ __launch_bounds__(1024) void k_scanA(
    const int* __restrict__ deg, int* __restrict__ incl, int* __restrict__ bsum, int N)
{
    __shared__ int s[1024];
    const int tid = threadIdx.x;
    const int i   = blockIdx.x * 1024 + tid;
    s[tid] = (i < N) ? deg[i] : 0;
    __syncthreads();
#pragma unroll
    for (int off = 1; off < 1024; off <<= 1) {
        int add = (tid >= off) ? s[tid - off] : 0;
        __syncthreads();
        s[tid] += add;
        __syncthreads();
    }
    if (i < N) incl[i] = s[tid];
    if (tid == 1023) bsum[blockIdx.x] = s[1023];
}

__global__ void k_scanB(int* __restrict__ bsum, int nb)
{
    if (threadIdx.x == 0 && blockIdx.x == 0) {
        int acc = 0;
        for (int b = 0; b < nb; ++b) { int v = bsum[b]; bsum[b] = acc; acc += v; }
    }
}

__global__ void k_cursor(const int* __restrict__ incl, const int* __restrict__ deg,
                         const int* __restrict__ bsum, int* __restrict__ cursor, int N)
{
    int i = blockIdx.x * 256 + threadIdx.x;
    if (i < N) cursor[i] = incl[i] - deg[i] + bsum[i >> 10];   // exclusive start
}

__global__ void k_fill(const int* __restrict__ ei, int E, int N,
                       int* __restrict__ cursor, int* __restrict__ col)
{
    int e = blockIdx.x * 256 + threadIdx.x;
    if (e < E) {
        int s = ei[e];        // row 0 = src
        int d = ei[E + e];    // row 1 = dst
        int pos = atomicAdd(&cursor[d], 1);
        col[pos] = s;
    } else if (e < E + N) {
        int n = e - E;        // self-loop
        int pos = atomicAdd(&cursor[n], 1);
        col[pos] = n;
    }
}

// ---------------------------------------------------------------------------
// K8: per-node online-softmax aggregation + bias + SiLU + LayerNorm
// one wave (64 lanes) per node; lane l owns channels 2l, 2l+1 (head = l>>4)
// ---------------------------------------------------------------------------
__global__ __launch_bounds__(256) void k_aggregate(
    const float* __restrict__ xl, const float* __restrict__ xr,
    const int* __restrict__ col, const int* __restrict__ cursor,
    const int* __restrict__ deg,
    const float* __restrict__ att, const float* __restrict__ bias,
    const float* __restrict__ gamma, const float* __restrict__ beta,
    float* __restrict__ out, int N)
{
    const int wid  = threadIdx.x >> 6;
    const int lane = threadIdx.x & 63;
    const int n    = blockIdx.x * 4 + wid;
    if (n >= N) return;

    const int end   = cursor[n];          // after fill: start + deg
    const int start = end - deg[n];

    const int c = 2 * lane;
    const float2 xrv = *(const float2*)&xr[(size_t)n * CH + c];
    const float2 av  = *(const float2*)&att[c];   // att flat [h][32] -> idx 2*lane

    float  m    = -INFINITY;
    float  lsum = 0.f;
    float2 acc  = make_float2(0.f, 0.f);

    for (int p = start; p < end; ++p) {
        int s = col[p];
        float2 v = *(const float2*)&xl[(size_t)s * CH + c];   // coalesced 512B/wave
        float ex = v.x + xrv.x;
        float ey = v.y + xrv.y;
        ex = ex > 0.f ? ex : NEG_SLOPE * ex;
        ey = ey > 0.f ? ey : NEG_SLOPE * ey;
        float part = ex * av.x + ey * av.y;
        // reduce across the 16 lanes of this head
        part += __shfl_xor(part, 1);
        part += __shfl_xor(part, 2);
        part += __shfl_xor(part, 4);
        part += __shfl_xor(part, 8);
        // online softmax update
        float mn    = fmaxf(m, part);
        float scale = __expf(m - mn);     // first iter: exp(-inf)=0
        float pw    = __expf(part - mn);
        acc.x = acc.x * scale + pw * v.x;
        acc.y = acc.y * scale + pw * v.y;
        lsum  = lsum * scale + pw;
        m = mn;
    }

    const float inv = 1.f / lsum;
    float y0 = acc.x * inv + bias[c];
    float y1 = acc.y * inv + bias[c + 1];
    // SiLU
    y0 = y0 / (1.f + __expf(-y0));
    y1 = y1 / (1.f + __expf(-y1));
    // LayerNorm across all 128 channels (64-lane reduce)
    float s1 = y0 + y1;
    float s2 = y0 * y0 + y1 * y1;
#pragma unroll
    for (int off = 1; off < 64; off <<= 1) {
        s1 += __shfl_xor(s1, off);
        s2 += __shfl_xor(s2, off);
    }
    float mu   = s1 * (1.f / 128.f);
    float var  = s2 * (1.f / 128.f) - mu * mu;
    float rstd = rsqrtf(var + LN_EPS);
    float o0 = (y0 - mu) * rstd * gamma[c]     + beta[c];
    float o1 = (y1 - mu) * rstd * gamma[c + 1] + beta[c + 1];
    out[(size_t)n * CH + c]     = o0;
    out[(size_t)n * CH + c + 1] = o1;
}

// ---------------------------------------------------------------------------
extern "C" void kernel_launch(void* const* d_in, const int* in_sizes, int n_in,
                              void* d_out, int out_size, void* d_ws, size_t ws_size,
                              hipStream_t stream)
{
    const float* x    = (const float*)d_in[0];
    const int*   ei   = (const int*)  d_in[1];
    const float* Wl   = (const float*)d_in[2];
    const float* bl   = (const float*)d_in[3];
    const float* Wr   = (const float*)d_in[4];
    const float* br   = (const float*)d_in[5];
    const float* att  = (const float*)d_in[6];
    const float* bias = (const float*)d_in[7];
    const float* gam  = (const float*)d_in[8];
    const float* bet  = (const float*)d_in[9];
    float* out = (float*)d_out;

    const int N = in_sizes[0] / CH;       // 50000
    const int E = in_sizes[1] / 2;        // 800000
    const int EN = E + N;                 // CSR slots

    // workspace carve (256B aligned)
    char* ws = (char*)d_ws;
    size_t off = 0;
    auto carve = [&](size_t bytes) -> char* {
        char* p = ws + off;
        off += (bytes + 255) & ~(size_t)255;
        return p;
    };
    float* xl     = (float*)carve((size_t)N * CH * sizeof(float));
    float* xr     = (float*)carve((size_t)N * CH * sizeof(float));
    int*   deg    = (int*)  carve((size_t)N * sizeof(int));
    int*   incl   = (int*)  carve((size_t)N * sizeof(int));
    int*   bsum   = (int*)  carve(256 * sizeof(int));
    int*   cursor = (int*)  carve((size_t)N * sizeof(int));
    int*   colidx = (int*)  carve((size_t)EN * sizeof(int));
    (void)ws_size;

    const int nchunks = (N + 1023) / 1024;

    k_transform<<<(N + 7) / 8, 256, 0, stream>>>(x, Wl, bl, Wr, br, xl, xr, N);
    k_deg_init <<<(N + 255) / 256, 256, 0, stream>>>(deg, N);
    k_count    <<<(E + 255) / 256, 256, 0, stream>>>(ei, E, deg);
    k_scanA    <<<nchunks, 1024, 0, stream>>>(deg, incl, bsum, N);
    k_scanB    <<<1, 64, 0, stream>>>(bsum, nchunks);
    k_cursor   <<<(N + 255) / 256, 256, 0, stream>>>(incl, deg, bsum, cursor, N);
    k_fill     <<<(EN + 255) / 256, 256, 0, stream>>>(ei, E, N, cursor, colidx);
    k_aggregate<<<(N + 3) / 4, 256, 0, stream>>>(xl, xr, colidx, cursor, deg,
                                                 att, bias, gam, bet, out, N);
}

// Round 2
// 336.058 us; speedup vs baseline: 1.1028x; 1.1028x over previous
//
#include <hip/hip_runtime.h>
#include <hip/hip_bf16.h>
#include <math.h>

#define CH 128          // IN_CH == OUT_CH == 128
#define NEG_SLOPE 0.2f
#define LN_EPS 1e-5f

typedef __attribute__((ext_vector_type(8))) short bf16x8;
typedef __attribute__((ext_vector_type(4))) float f32x4;

__device__ __forceinline__ unsigned short f2bf(float f) {
    union { float f; unsigned u; } v; v.f = f;
    unsigned u = v.u;
    unsigned r = (u + 0x7FFF + ((u >> 16) & 1)) >> 16;   // RNE
    return (unsigned short)r;
}

// ---------------------------------------------------------------------------
// Prep: Wt_bf[col][k] = bf16( col<128 ? Wl[k][col] : Wr[k][col-128] )
// 256 cols x 128 k = 32768 elems; reads coalesced over col.
// ---------------------------------------------------------------------------
__global__ void k_wcat(const float* __restrict__ Wl, const float* __restrict__ Wr,
                       unsigned short* __restrict__ Wt)
{
    int tid = blockIdx.x * 256 + threadIdx.x;      // 0..32767
    if (tid >= 256 * CH) return;
    int k   = tid >> 8;
    int col = tid & 255;
    float w = (col < CH) ? Wl[k * CH + col] : Wr[k * CH + (col - CH)];
    Wt[(size_t)col * CH + k] = f2bf(w);
}

// ---------------------------------------------------------------------------
// K1: MFMA bf16 GEMM. One wave computes 16 nodes x 256 cols (K=128).
// cols 0..127 -> xl (stored bf16), cols 128..255 -> xr (fp32).
// A loaded from fp32 x, converted in-register. B from L1/L2-hot Wt.
// ---------------------------------------------------------------------------
__global__ __launch_bounds__(256) void k_transform(
    const float* __restrict__ x, const unsigned short* __restrict__ Wt,
    const float* __restrict__ bl, const float* __restrict__ br,
    unsigned short* __restrict__ xlb, float* __restrict__ xr, int N)
{
    const int wave = (blockIdx.x * 256 + threadIdx.x) >> 6;
    const int lane = threadIdx.x & 63;
    const int m0   = wave * 16;
    if (m0 >= N) return;

    const int n16  = lane & 15;     // A: m index / B: n index / D: col index
    const int quad = lane >> 4;

    // A fragments for all 4 K-steps: x[m0+n16][ks*32 + quad*8 + j]
    bf16x8 afr[4];
    const float* xrow = x + (size_t)(m0 + n16) * CH + quad * 8;
#pragma unroll
    for (int ks = 0; ks < 4; ++ks) {
        float4 p0 = *(const float4*)(xrow + ks * 32);
        float4 p1 = *(const float4*)(xrow + ks * 32 + 4);
        afr[ks][0] = (short)f2bf(p0.x); afr[ks][1] = (short)f2bf(p0.y);
        afr[ks][2] = (short)f2bf(p0.z); afr[ks][3] = (short)f2bf(p0.w);
        afr[ks][4] = (short)f2bf(p1.x); afr[ks][5] = (short)f2bf(p1.y);
        afr[ks][6] = (short)f2bf(p1.z); afr[ks][7] = (short)f2bf(p1.w);
    }

#pragma unroll
    for (int ct = 0; ct < 16; ++ct) {
        f32x4 acc = {0.f, 0.f, 0.f, 0.f};
        const int col = ct * 16 + n16;
        const unsigned short* wp = Wt + (size_t)col * CH + quad * 8;
#pragma unroll
        for (int ks = 0; ks < 4; ++ks) {
            bf16x8 bfr = *(const bf16x8*)(wp + ks * 32);
            acc = __builtin_amdgcn_mfma_f32_16x16x32_bf16(afr[ks], bfr, acc, 0, 0, 0);
        }
        if (ct < 8) {
            float bb = bl[col];
#pragma unroll
            for (int r = 0; r < 4; ++r) {
                int node = m0 + quad * 4 + r;
                xlb[(size_t)node * CH + col] = f2bf(acc[r] + bb);
            }
        } else {
            int cc = col - CH;
            float bb = br[cc];
#pragma unroll
            for (int r = 0; r < 4; ++r) {
                int node = m0 + quad * 4 + r;
                xr[(size_t)node * CH + cc] = acc[r] + bb;
            }
        }
    }
}

// ---------------------------------------------------------------------------
// CSR build: deg init (self-loop=1) -> count -> 2-level scan -> cursor -> fill
// ---------------------------------------------------------------------------
__global__ void k_deg_init(int* __restrict__ deg, int N)
{
    int i = blockIdx.x * 256 + threadIdx.x;
    if (i < N) deg[i] = 1;   // self-loop
}

__global__ void k_count(const int* __restrict__ ei, int E, int* __restrict__ deg)
{
    int e = blockIdx.x * 256 + threadIdx.x;
    if (e < E) {
        int d = ei[E + e];   // row 1 = dst
        atomicAdd(&deg[d], 1);
    }
}

__global__ __launch_bounds__(1024) void k_scanA(
    const int* __restrict__ deg, int* __restrict__ incl, int* __restrict__ bsum, int N)
{
    __shared__ int s[1024];
    const int tid = threadIdx.x;
    const int i   = blockIdx.x * 1024 + tid;
    s[tid] = (i < N) ? deg[i] : 0;
    __syncthreads();
#pragma unroll
    for (int off = 1; off < 1024; off <<= 1) {
        int add = (tid >= off) ? s[tid - off] : 0;
        __syncthreads();
        s[tid] += add;
        __syncthreads();
    }
    if (i < N) incl[i] = s[tid];
    if (tid == 1023) bsum[blockIdx.x] = s[1023];
}

__global__ void k_scanB(int* __restrict__ bsum, int nb)
{
    if (threadIdx.x == 0 && blockIdx.x == 0) {
        int acc = 0;
        for (int b = 0; b < nb; ++b) { int v = bsum[b]; bsum[b] = acc; acc += v; }
    }
}

__global__ void k_cursor(const int* __restrict__ incl, const int* __restrict__ deg,
                         const int* __restrict__ bsum, int* __restrict__ cursor, int N)
{
    int i = blockIdx.x * 256 + threadIdx.x;
    if (i < N) cursor[i] = incl[i] - deg[i] + bsum[i >> 10];   // exclusive start
}

__global__ void k_fill(const int* __restrict__ ei, int E, int N,
                       int* __restrict__ cursor, int* __restrict__ col)
{
    int e = blockIdx.x * 256 + threadIdx.x;
    if (e < E) {
        int s = ei[e];        // row 0 = src
        int d = ei[E + e];    // row 1 = dst
        int pos = atomicAdd(&cursor[d], 1);
        col[pos] = s;
    } else if (e < E + N) {
        int n = e - E;        // self-loop
        int pos = atomicAdd(&cursor[n], 1);
        col[pos] = n;
    }
}

// ---------------------------------------------------------------------------
// K8: per-node online-softmax aggregation + bias + SiLU + LayerNorm
// one wave per node; lane l owns channels 2l, 2l+1 (head = l>>4).
// xl gathered as bf16 (halves the random-gather traffic).
// ---------------------------------------------------------------------------
__global__ __launch_bounds__(256) void k_aggregate(
    const unsigned short* __restrict__ xlb, const float* __restrict__ xr,
    const int* __restrict__ col, const int* __restrict__ cursor,
    const int* __restrict__ deg,
    const float* __restrict__ att, const float* __restrict__ bias,
    const float* __restrict__ gamma, const float* __restrict__ beta,
    float* __restrict__ out, int N)
{
    const int wid  = threadIdx.x >> 6;
    const int lane = threadIdx.x & 63;
    const int n    = blockIdx.x * 4 + wid;
    if (n >= N) return;

    const int end   = cursor[n];          // after fill: start + deg
    const int start = end - deg[n];

    const int c = 2 * lane;
    const float2 xrv = *(const float2*)&xr[(size_t)n * CH + c];
    const float2 av  = *(const float2*)&att[c];

    float  m    = -INFINITY;
    float  lsum = 0.f;
    float2 acc  = make_float2(0.f, 0.f);

    for (int p = start; p < end; ++p) {
        int s = col[p];
        unsigned u = *(const unsigned*)&xlb[(size_t)s * CH + c];   // 2 bf16, coalesced 256B/wave
        float vx = __uint_as_float(u << 16);
        float vy = __uint_as_float(u & 0xffff0000u);
        float ex = vx + xrv.x;
        float ey = vy + xrv.y;
        ex = ex > 0.f ? ex : NEG_SLOPE * ex;
        ey = ey > 0.f ? ey : NEG_SLOPE * ey;
        float part = ex * av.x + ey * av.y;
        // reduce across the 16 lanes of this head
        part += __shfl_xor(part, 1);
        part += __shfl_xor(part, 2);
        part += __shfl_xor(part, 4);
        part += __shfl_xor(part, 8);
        // online softmax update
        float mn    = fmaxf(m, part);
        float scale = __expf(m - mn);     // first iter: exp(-inf)=0
        float pw    = __expf(part - mn);
        acc.x = acc.x * scale + pw * vx;
        acc.y = acc.y * scale + pw * vy;
        lsum  = lsum * scale + pw;
        m = mn;
    }

    const float inv = 1.f / lsum;
    float y0 = acc.x * inv + bias[c];
    float y1 = acc.y * inv + bias[c + 1];
    // SiLU
    y0 = y0 / (1.f + __expf(-y0));
    y1 = y1 / (1.f + __expf(-y1));
    // LayerNorm across 128 channels (full-wave reduce)
    float s1 = y0 + y1;
    float s2 = y0 * y0 + y1 * y1;
#pragma unroll
    for (int off = 1; off < 64; off <<= 1) {
        s1 += __shfl_xor(s1, off);
        s2 += __shfl_xor(s2, off);
    }
    float mu   = s1 * (1.f / 128.f);
    float var  = s2 * (1.f / 128.f) - mu * mu;
    float rstd = rsqrtf(var + LN_EPS);
    float o0 = (y0 - mu) * rstd * gamma[c]     + beta[c];
    float o1 = (y1 - mu) * rstd * gamma[c + 1] + beta[c + 1];
    out[(size_t)n * CH + c]     = o0;
    out[(size_t)n * CH + c + 1] = o1;
}

// ---------------------------------------------------------------------------
extern "C" void kernel_launch(void* const* d_in, const int* in_sizes, int n_in,
                              void* d_out, int out_size, void* d_ws, size_t ws_size,
                              hipStream_t stream)
{
    const float* x    = (const float*)d_in[0];
    const int*   ei   = (const int*)  d_in[1];
    const float* Wl   = (const float*)d_in[2];
    const float* bl   = (const float*)d_in[3];
    const float* Wr   = (const float*)d_in[4];
    const float* br   = (const float*)d_in[5];
    const float* att  = (const float*)d_in[6];
    const float* bias = (const float*)d_in[7];
    const float* gam  = (const float*)d_in[8];
    const float* bet  = (const float*)d_in[9];
    float* out = (float*)d_out;

    const int N = in_sizes[0] / CH;       // 50000
    const int E = in_sizes[1] / 2;        // 800000
    const int EN = E + N;                 // CSR slots

    // workspace carve (256B aligned)
    char* ws = (char*)d_ws;
    size_t off = 0;
    auto carve = [&](size_t bytes) -> char* {
        char* p = ws + off;
        off += (bytes + 255) & ~(size_t)255;
        return p;
    };
    unsigned short* xlb = (unsigned short*)carve((size_t)N * CH * sizeof(unsigned short));
    float* xr     = (float*)carve((size_t)N * CH * sizeof(float));
    unsigned short* Wt = (unsigned short*)carve((size_t)256 * CH * sizeof(unsigned short));
    int*   deg    = (int*)  carve((size_t)N * sizeof(int));
    int*   incl   = (int*)  carve((size_t)N * sizeof(int));
    int*   bsum   = (int*)  carve(256 * sizeof(int));
    int*   cursor = (int*)  carve((size_t)N * sizeof(int));
    int*   colidx = (int*)  carve((size_t)EN * sizeof(int));
    (void)ws_size;

    const int nchunks = (N + 1023) / 1024;
    const int nwaves  = (N + 15) / 16;                 // GEMM waves
    const int tblocks = (nwaves * 64 + 255) / 256;

    k_wcat     <<<(256 * CH + 255) / 256, 256, 0, stream>>>(Wl, Wr, Wt);
    k_transform<<<tblocks, 256, 0, stream>>>(x, Wt, bl, br, xlb, xr, N);
    k_deg_init <<<(N + 255) / 256, 256, 0, stream>>>(deg, N);
    k_count    <<<(E + 255) / 256, 256, 0, stream>>>(ei, E, deg);
    k_scanA    <<<nchunks, 1024, 0, stream>>>(deg, incl, bsum, N);
    k_scanB    <<<1, 64, 0, stream>>>(bsum, nchunks);
    k_cursor   <<<(N + 255) / 256, 256, 0, stream>>>(incl, deg, bsum, cursor, N);
    k_fill     <<<(EN + 255) / 256, 256, 0, stream>>>(ei, E, N, cursor, colidx);
    k_aggregate<<<(N + 3) / 4, 256, 0, stream>>>(xlb, xr, colidx, cursor, deg,
                                                 att, bias, gam, bet, out, N);
}

// Round 3
// 322.713 us; speedup vs baseline: 1.1484x; 1.0414x over previous
//
#include <hip/hip_runtime.h>
#include <hip/hip_bf16.h>
#include <math.h>

#define CH 128          // IN_CH == OUT_CH == 128
#define NEG_SLOPE 0.2f
#define LN_EPS 1e-5f

typedef __attribute__((ext_vector_type(8))) short bf16x8;
typedef __attribute__((ext_vector_type(4))) float f32x4;

__device__ __forceinline__ unsigned short f2bf(float f) {
    union { float f; unsigned u; } v; v.f = f;
    unsigned u = v.u;
    unsigned r = (u + 0x7FFF + ((u >> 16) & 1)) >> 16;   // RNE
    return (unsigned short)r;
}
__device__ __forceinline__ float bflo(unsigned u) { return __uint_as_float(u << 16); }
__device__ __forceinline__ float bfhi(unsigned u) { return __uint_as_float(u & 0xffff0000u); }

// ---------------------------------------------------------------------------
// Prep: Wt[col][k] = bf16(col<128 ? Wl[k][col] : Wr[k][col-128]);  deg[i]=1
// ---------------------------------------------------------------------------
__global__ void k_prep(const float* __restrict__ Wl, const float* __restrict__ Wr,
                       unsigned short* __restrict__ Wt, int* __restrict__ deg, int N)
{
    int tid = blockIdx.x * 256 + threadIdx.x;
    if (tid < 256 * CH) {
        int k   = tid >> 8;
        int col = tid & 255;
        float w = (col < CH) ? Wl[k * CH + col] : Wr[k * CH + (col - CH)];
        Wt[(size_t)col * CH + k] = f2bf(w);
    }
    if (tid < N) deg[tid] = 1;   // self-loop
}

// ---------------------------------------------------------------------------
// K1: MFMA bf16 GEMM; wave computes 16 nodes x 256 cols (K=128).
// cols 0..127 -> xlb (bf16), cols 128..255 -> xrb (bf16).
// ---------------------------------------------------------------------------
__global__ __launch_bounds__(256) void k_transform(
    const float* __restrict__ x, const unsigned short* __restrict__ Wt,
    const float* __restrict__ bl, const float* __restrict__ br,
    unsigned short* __restrict__ xlb, unsigned short* __restrict__ xrb, int N)
{
    const int wave = (blockIdx.x * 256 + threadIdx.x) >> 6;
    const int lane = threadIdx.x & 63;
    const int m0   = wave * 16;
    if (m0 >= N) return;

    const int n16  = lane & 15;
    const int quad = lane >> 4;

    bf16x8 afr[4];
    const float* xrow = x + (size_t)(m0 + n16) * CH + quad * 8;
#pragma unroll
    for (int ks = 0; ks < 4; ++ks) {
        float4 p0 = *(const float4*)(xrow + ks * 32);
        float4 p1 = *(const float4*)(xrow + ks * 32 + 4);
        afr[ks][0] = (short)f2bf(p0.x); afr[ks][1] = (short)f2bf(p0.y);
        afr[ks][2] = (short)f2bf(p0.z); afr[ks][3] = (short)f2bf(p0.w);
        afr[ks][4] = (short)f2bf(p1.x); afr[ks][5] = (short)f2bf(p1.y);
        afr[ks][6] = (short)f2bf(p1.z); afr[ks][7] = (short)f2bf(p1.w);
    }

#pragma unroll
    for (int ct = 0; ct < 16; ++ct) {
        f32x4 acc = {0.f, 0.f, 0.f, 0.f};
        const int col = ct * 16 + n16;
        const unsigned short* wp = Wt + (size_t)col * CH + quad * 8;
#pragma unroll
        for (int ks = 0; ks < 4; ++ks) {
            bf16x8 bfr = *(const bf16x8*)(wp + ks * 32);
            acc = __builtin_amdgcn_mfma_f32_16x16x32_bf16(afr[ks], bfr, acc, 0, 0, 0);
        }
        if (ct < 8) {
            float bb = bl[col];
#pragma unroll
            for (int r = 0; r < 4; ++r) {
                int node = m0 + quad * 4 + r;
                xlb[(size_t)node * CH + col] = f2bf(acc[r] + bb);
            }
        } else {
            int cc = col - CH;
            float bb = br[cc];
#pragma unroll
            for (int r = 0; r < 4; ++r) {
                int node = m0 + quad * 4 + r;
                xrb[(size_t)node * CH + cc] = f2bf(acc[r] + bb);
            }
        }
    }
}

// ---------------------------------------------------------------------------
// CSR build
// ---------------------------------------------------------------------------
__global__ void k_count(const int* __restrict__ ei, int E, int* __restrict__ deg)
{
    int e = blockIdx.x * 256 + threadIdx.x;
    if (e < E) atomicAdd(&deg[ei[E + e]], 1);
}

__global__ __launch_bounds__(1024) void k_scanA(
    const int* __restrict__ deg, int* __restrict__ incl, int* __restrict__ bsum, int N)
{
    __shared__ int s[1024];
    const int tid = threadIdx.x;
    const int i   = blockIdx.x * 1024 + tid;
    s[tid] = (i < N) ? deg[i] : 0;
    __syncthreads();
#pragma unroll
    for (int off = 1; off < 1024; off <<= 1) {
        int add = (tid >= off) ? s[tid - off] : 0;
        __syncthreads();
        s[tid] += add;
        __syncthreads();
    }
    if (i < N) incl[i] = s[tid];
    if (tid == 1023) bsum[blockIdx.x] = s[1023];
}

// wave-parallel exclusive scan of block sums (nb can exceed 64 via carry loop)
__global__ void k_scanB(int* __restrict__ bsum, int nb)
{
    int lane = threadIdx.x;   // 64 threads, 1 block
    int carry = 0;
    for (int base = 0; base < nb; base += 64) {
        int i = base + lane;
        int v = (i < nb) ? bsum[i] : 0;
        int incl = v;
#pragma unroll
        for (int off = 1; off < 64; off <<= 1) {
            int t = __shfl_up(incl, off);
            if (lane >= off) incl += t;
        }
        if (i < nb) bsum[i] = carry + incl - v;   // exclusive
        carry += __shfl(incl, 63);
    }
}

__global__ void k_cursor(const int* __restrict__ incl, const int* __restrict__ deg,
                         const int* __restrict__ bsum, int* __restrict__ cursor, int N)
{
    int i = blockIdx.x * 256 + threadIdx.x;
    if (i < N) cursor[i] = incl[i] - deg[i] + bsum[i >> 10];
}

__global__ void k_fill(const int* __restrict__ ei, int E, int N,
                       int* __restrict__ cursor, int* __restrict__ col)
{
    int e = blockIdx.x * 256 + threadIdx.x;
    if (e < E) {
        int s = ei[e];
        int d = ei[E + e];
        int pos = atomicAdd(&cursor[d], 1);
        col[pos] = s;
    } else if (e < E + N) {
        int n = e - E;
        int pos = atomicAdd(&cursor[n], 1);
        col[pos] = n;
    }
}

// ---------------------------------------------------------------------------
// K8: batched online-softmax aggregation + bias + SiLU + LayerNorm.
// One wave per node; edges processed 16/batch.
//   Phase A (lane = e*4+h): gather 16 rows (64B/lane), stage to LDS, compute
//           head-score fully in-lane (no shuffles).
//   Phase B: one 16-lane max-reduce + sum-reduce per batch (8 shuffles total),
//           one exp pair per lane per batch.
//   Phase C (lane owns ch 2l,2l+1): acc += w[e,h] * row from LDS (L1-free).
// LDS row stride 136 u16 (272B): A-writes 4-way conflict (1.58x), C-reads 2-way (free).
// ---------------------------------------------------------------------------
#define XROW 136   // u16 stride per staged row

__global__ __launch_bounds__(256) void k_aggregate(
    const unsigned short* __restrict__ xlb, const unsigned short* __restrict__ xrb,
    const int* __restrict__ col, const int* __restrict__ cursor,
    const int* __restrict__ deg,
    const float* __restrict__ att, const float* __restrict__ bias,
    const float* __restrict__ gamma, const float* __restrict__ beta,
    float* __restrict__ out, int N)
{
    __shared__ unsigned short xbuf[4][16 * XROW];
    __shared__ float wbuf[4][64];
    __shared__ float fbuf[4][4];
    __shared__ float lbuf[4][4];

    const int wid  = threadIdx.x >> 6;
    const int lane = threadIdx.x & 63;
    const int n    = blockIdx.x * 4 + wid;
    if (n >= N) return;

    const int end   = cursor[n];
    const int start = end - deg[n];

    const int eB = lane >> 2;   // edge slot 0..15 (phase A/B)
    const int hB = lane & 3;    // head (phase A/B)
    const int hC = lane >> 4;   // head (phase C)

    // per-lane constants: xr & att slices for head hB (32 ch each)
    float xr_s[32], att_s[32];
    {
        const uint4* xp = (const uint4*)(xrb + (size_t)n * CH + hB * 32);
#pragma unroll
        for (int j = 0; j < 4; ++j) {
            uint4 q = xp[j];
            unsigned uu[4] = {q.x, q.y, q.z, q.w};
#pragma unroll
            for (int w = 0; w < 4; ++w) {
                xr_s[j * 8 + 2 * w]     = bflo(uu[w]);
                xr_s[j * 8 + 2 * w + 1] = bfhi(uu[w]);
            }
        }
        const float4* ap = (const float4*)(att + hB * 32);
#pragma unroll
        for (int j = 0; j < 8; ++j) {
            float4 a = ap[j];
            att_s[j * 4]     = a.x; att_s[j * 4 + 1] = a.y;
            att_s[j * 4 + 2] = a.z; att_s[j * 4 + 3] = a.w;
        }
    }

    float  m_run = -INFINITY;
    float  l_run = 0.f;
    float2 acc   = make_float2(0.f, 0.f);

    for (int p0 = start; p0 < end; p0 += 16) {
        // ---- Phase A: gather + stage + in-lane score ----
        int pe = p0 + eB;
        int pc = pe < end ? pe : end - 1;
        int src = col[pc];
        const uint4* gp = (const uint4*)(xlb + (size_t)src * CH + hB * 32);
        uint4 q0 = gp[0], q1 = gp[1], q2 = gp[2], q3 = gp[3];

        unsigned short* xw = &xbuf[wid][eB * XROW + hB * 32];
        *(uint4*)(xw)      = q0;
        *(uint4*)(xw + 8)  = q1;
        *(uint4*)(xw + 16) = q2;
        *(uint4*)(xw + 24) = q3;

        float s = 0.f;
        {
            uint4 qs[4] = {q0, q1, q2, q3};
#pragma unroll
            for (int j = 0; j < 4; ++j) {
                unsigned uu[4] = {qs[j].x, qs[j].y, qs[j].z, qs[j].w};
#pragma unroll
                for (int w = 0; w < 4; ++w) {
                    int idx = j * 8 + 2 * w;
                    float t0 = bflo(uu[w]) + xr_s[idx];
                    float t1 = bfhi(uu[w]) + xr_s[idx + 1];
                    t0 = fmaxf(t0, NEG_SLOPE * t0);   // leaky_relu
                    t1 = fmaxf(t1, NEG_SLOPE * t1);
                    s = fmaf(t0, att_s[idx], s);
                    s = fmaf(t1, att_s[idx + 1], s);
                }
            }
        }
        if (pe >= end) s = -INFINITY;

        // ---- Phase B: batch max/sum reduce (over e-lanes, stride 4) ----
        float bm = s;
        bm = fmaxf(bm, __shfl_xor(bm, 4));
        bm = fmaxf(bm, __shfl_xor(bm, 8));
        bm = fmaxf(bm, __shfl_xor(bm, 16));
        bm = fmaxf(bm, __shfl_xor(bm, 32));
        float m_new = fmaxf(m_run, bm);
        float w  = __expf(s - m_new);        // -inf -> 0
        float fr = __expf(m_run - m_new);    // first batch: 0
        float ws = w;
        ws += __shfl_xor(ws, 4);
        ws += __shfl_xor(ws, 8);
        ws += __shfl_xor(ws, 16);
        ws += __shfl_xor(ws, 32);
        l_run = l_run * fr + ws;
        m_run = m_new;

        wbuf[wid][lane] = w;                 // (e,h) -> slot e*4+h == lane
        if (eB == 0) fbuf[wid][hB] = fr;

        // ---- Phase C: weighted accumulate from LDS ----
        float fc = fbuf[wid][hC];
        acc.x *= fc; acc.y *= fc;
        int rem  = end - p0;
        int emax = rem < 16 ? rem : 16;
        int e = 0;
        for (; e + 4 <= emax; e += 4) {
#pragma unroll
            for (int k = 0; k < 4; ++k) {
                float we = wbuf[wid][(e + k) * 4 + hC];
                unsigned u = *(const unsigned*)&xbuf[wid][(e + k) * XROW + lane * 2];
                acc.x = fmaf(we, bflo(u), acc.x);
                acc.y = fmaf(we, bfhi(u), acc.y);
            }
        }
        for (; e < emax; ++e) {
            float we = wbuf[wid][e * 4 + hC];
            unsigned u = *(const unsigned*)&xbuf[wid][e * XROW + lane * 2];
            acc.x = fmaf(we, bflo(u), acc.x);
            acc.y = fmaf(we, bfhi(u), acc.y);
        }
    }

    // publish per-head lsum, read in phase-C layout
    if (lane < 4) lbuf[wid][lane] = l_run;
    float l_c = lbuf[wid][hC];

    const int c = 2 * lane;
    const float inv = 1.f / l_c;
    float y0 = acc.x * inv + bias[c];
    float y1 = acc.y * inv + bias[c + 1];
    y0 = y0 / (1.f + __expf(-y0));   // SiLU
    y1 = y1 / (1.f + __expf(-y1));
    float s1 = y0 + y1;
    float s2 = y0 * y0 + y1 * y1;
#pragma unroll
    for (int off = 1; off < 64; off <<= 1) {
        s1 += __shfl_xor(s1, off);
        s2 += __shfl_xor(s2, off);
    }
    float mu   = s1 * (1.f / 128.f);
    float var  = s2 * (1.f / 128.f) - mu * mu;
    float rstd = rsqrtf(var + LN_EPS);
    out[(size_t)n * CH + c]     = (y0 - mu) * rstd * gamma[c]     + beta[c];
    out[(size_t)n * CH + c + 1] = (y1 - mu) * rstd * gamma[c + 1] + beta[c + 1];
}

// ---------------------------------------------------------------------------
extern "C" void kernel_launch(void* const* d_in, const int* in_sizes, int n_in,
                              void* d_out, int out_size, void* d_ws, size_t ws_size,
                              hipStream_t stream)
{
    const float* x    = (const float*)d_in[0];
    const int*   ei   = (const int*)  d_in[1];
    const float* Wl   = (const float*)d_in[2];
    const float* bl   = (const float*)d_in[3];
    const float* Wr   = (const float*)d_in[4];
    const float* br   = (const float*)d_in[5];
    const float* att  = (const float*)d_in[6];
    const float* bias = (const float*)d_in[7];
    const float* gam  = (const float*)d_in[8];
    const float* bet  = (const float*)d_in[9];
    float* out = (float*)d_out;

    const int N  = in_sizes[0] / CH;      // 50000
    const int E  = in_sizes[1] / 2;       // 800000
    const int EN = E + N;

    char* ws = (char*)d_ws;
    size_t off = 0;
    auto carve = [&](size_t bytes) -> char* {
        char* p = ws + off;
        off += (bytes + 255) & ~(size_t)255;
        return p;
    };
    unsigned short* xlb = (unsigned short*)carve((size_t)N * CH * sizeof(unsigned short));
    unsigned short* xrb = (unsigned short*)carve((size_t)N * CH * sizeof(unsigned short));
    unsigned short* Wt  = (unsigned short*)carve((size_t)256 * CH * sizeof(unsigned short));
    int* deg    = (int*)carve((size_t)N * sizeof(int));
    int* incl   = (int*)carve((size_t)N * sizeof(int));
    int* bsum   = (int*)carve(256 * sizeof(int));
    int* cursor = (int*)carve((size_t)N * sizeof(int));
    int* colidx = (int*)carve((size_t)EN * sizeof(int));
    (void)ws_size;

    const int nchunks = (N + 1023) / 1024;
    const int nwaves  = (N + 15) / 16;
    const int tblocks = (nwaves * 64 + 255) / 256;

    k_prep     <<<(N + 255) / 256, 256, 0, stream>>>(Wl, Wr, Wt, deg, N);
    k_transform<<<tblocks, 256, 0, stream>>>(x, Wt, bl, br, xlb, xrb, N);
    k_count    <<<(E + 255) / 256, 256, 0, stream>>>(ei, E, deg);
    k_scanA    <<<nchunks, 1024, 0, stream>>>(deg, incl, bsum, N);
    k_scanB    <<<1, 64, 0, stream>>>(bsum, nchunks);
    k_cursor   <<<(N + 255) / 256, 256, 0, stream>>>(incl, deg, bsum, cursor, N);
    k_fill     <<<(EN + 255) / 256, 256, 0, stream>>>(ei, E, N, cursor, colidx);
    k_aggregate<<<(N + 3) / 4, 256, 0, stream>>>(xlb, xrb, colidx, cursor, deg,
                                                 att, bias, gam, bet, out, N);
}

// Round 4
// 305.192 us; speedup vs baseline: 1.2144x; 1.0574x over previous
//
#include <hip/hip_runtime.h>
#include <hip/hip_fp16.h>
#include <math.h>

#define CH 128          // IN_CH == OUT_CH == 128
#define NEG_SLOPE 0.2f
#define LN_EPS 1e-5f

typedef _Float16 f16;
typedef _Float16 f16x2 __attribute__((ext_vector_type(2)));
typedef _Float16 f16x8 __attribute__((ext_vector_type(8)));
typedef float    f32x4 __attribute__((ext_vector_type(4)));

__device__ __forceinline__ f16x2 u2h(unsigned u) {
    union { unsigned u; f16x2 h; } v; v.u = u; return v.h;
}

// ---------------------------------------------------------------------------
// K1: Wt[col][k] = f16(col<128 ? Wl[k][col] : Wr[k][col-128]);
//     deg[dst]++ for all edges (deg pre-zeroed by memsetAsync; self-loop
//     handled as deg+1 downstream).
// ---------------------------------------------------------------------------
__global__ void k_prep_count(const float* __restrict__ Wl, const float* __restrict__ Wr,
                             f16* __restrict__ Wt,
                             const int* __restrict__ ei, int E, int* __restrict__ deg)
{
    int tid = blockIdx.x * 256 + threadIdx.x;
    if (tid < 256 * CH) {
        int k   = tid >> 8;
        int col = tid & 255;
        float w = (col < CH) ? Wl[k * CH + col] : Wr[k * CH + (col - CH)];
        Wt[(size_t)col * CH + k] = (f16)w;
    }
    if (tid < E) atomicAdd(&deg[ei[E + tid]], 1);
}

// ---------------------------------------------------------------------------
// K2: MFMA f16 GEMM; wave computes 16 nodes x 256 cols (K=128).
// Operands swapped vs r3: A = W columns (m=channel), B = x rows (n=node)
// => D rows are channels: lane holds 4 CONSECUTIVE channels of one node
// => packed 8B stores instead of u16 scatter.
// ---------------------------------------------------------------------------
__global__ __launch_bounds__(256) void k_transform(
    const float* __restrict__ x, const f16* __restrict__ Wt,
    const float* __restrict__ bl, const float* __restrict__ br,
    f16* __restrict__ xlh, f16* __restrict__ xrh, int N)
{
    const int wave = (blockIdx.x * 256 + threadIdx.x) >> 6;
    const int lane = threadIdx.x & 63;
    const int m0   = wave * 16;
    if (m0 >= N) return;

    const int n16  = lane & 15;
    const int quad = lane >> 4;

    // B-frag: x rows, B[n=node][k=quad*8+j], cvt f32->f16 in-register
    f16x8 xfr[4];
    {
        int mrow = m0 + n16; if (mrow >= N) mrow = N - 1;
        const float* xrow = x + (size_t)mrow * CH + quad * 8;
#pragma unroll
        for (int ks = 0; ks < 4; ++ks) {
            float4 p0 = *(const float4*)(xrow + ks * 32);
            float4 p1 = *(const float4*)(xrow + ks * 32 + 4);
            f16x8 f; f[0] = (f16)p0.x; f[1] = (f16)p0.y; f[2] = (f16)p0.z; f[3] = (f16)p0.w;
                     f[4] = (f16)p1.x; f[5] = (f16)p1.y; f[6] = (f16)p1.z; f[7] = (f16)p1.w;
            xfr[ks] = f;
        }
    }

#pragma unroll
    for (int ct = 0; ct < 16; ++ct) {
        f32x4 acc = {0.f, 0.f, 0.f, 0.f};
        const int acol = ct * 16 + n16;                       // A row = channel
        const f16* wp = Wt + (size_t)acol * CH + quad * 8;
#pragma unroll
        for (int ks = 0; ks < 4; ++ks) {
            f16x8 afr = *(const f16x8*)(wp + ks * 32);
            acc = __builtin_amdgcn_mfma_f32_16x16x32_f16(afr, xfr[ks], acc, 0, 0, 0);
        }
        // D[row=quad*4+r][col=n16]: row = channel-in-tile, col = node
        const int node = m0 + n16;
        const int chq  = ct * 16 + quad * 4;                  // first of 4 consecutive ch
        if (node < N) {
            if (ct < 8) {
                float4 bv = *(const float4*)&bl[chq];
                f16x2 p0 = {(f16)(acc[0] + bv.x), (f16)(acc[1] + bv.y)};
                f16x2 p1 = {(f16)(acc[2] + bv.z), (f16)(acc[3] + bv.w)};
                f16* dst = xlh + (size_t)node * CH + chq;
                *(f16x2*)dst = p0; *(f16x2*)(dst + 2) = p1;
            } else {
                int cc = chq - CH;
                float4 bv = *(const float4*)&br[cc];
                f16x2 p0 = {(f16)(acc[0] + bv.x), (f16)(acc[1] + bv.y)};
                f16x2 p1 = {(f16)(acc[2] + bv.z), (f16)(acc[3] + bv.w)};
                f16* dst = xrh + (size_t)node * CH + cc;
                *(f16x2*)dst = p0; *(f16x2*)(dst + 2) = p1;
            }
        }
    }
}

// ---------------------------------------------------------------------------
// CSR: scanA (deg+1, writes local-exclusive cursor) -> scanB -> fill
// ---------------------------------------------------------------------------
__global__ __launch_bounds__(1024) void k_scanA(
    const int* __restrict__ deg, int* __restrict__ cur, int* __restrict__ bsum, int N)
{
    __shared__ int s[1024];
    const int tid = threadIdx.x;
    const int i   = blockIdx.x * 1024 + tid;
    const int d1  = (i < N) ? deg[i] + 1 : 0;     // +1 = self-loop
    s[tid] = d1;
    __syncthreads();
#pragma unroll
    for (int off = 1; off < 1024; off <<= 1) {
        int add = (tid >= off) ? s[tid - off] : 0;
        __syncthreads();
        s[tid] += add;
        __syncthreads();
    }
    if (i < N) cur[i] = s[tid] - d1;              // local exclusive
    if (tid == 1023) bsum[blockIdx.x] = s[1023];
}

__global__ void k_scanB(int* __restrict__ bsum, int nb)
{
    int lane = threadIdx.x;   // 64 threads, 1 block
    int carry = 0;
    for (int base = 0; base < nb; base += 64) {
        int i = base + lane;
        int v = (i < nb) ? bsum[i] : 0;
        int incl = v;
#pragma unroll
        for (int off = 1; off < 64; off <<= 1) {
            int t = __shfl_up(incl, off);
            if (lane >= off) incl += t;
        }
        if (i < nb) bsum[i] = carry + incl - v;   // exclusive
        carry += __shfl(incl, 63);
    }
}

__global__ void k_fill(const int* __restrict__ ei, int E, int N,
                       int* __restrict__ cur, const int* __restrict__ bsum,
                       int* __restrict__ col)
{
    int e = blockIdx.x * 256 + threadIdx.x;
    if (e < E) {
        int s = ei[e];
        int d = ei[E + e];
        int pos = atomicAdd(&cur[d], 1) + bsum[d >> 10];
        col[pos] = s;
    } else if (e < E + N) {
        int n = e - E;
        int pos = atomicAdd(&cur[n], 1) + bsum[n >> 10];
        col[pos] = n;
    }
}

// ---------------------------------------------------------------------------
// K6: aggregation + bias + SiLU + LayerNorm. One wave per node, 16 edges/batch.
// Phase A (lane=e*4+h): gather 64B f16 row-slice, stage to LDS, score via
//   v_pk_add_f16 / v_pk_mul / v_pk_max / v_dot2_f32_f16 (4 instr / 2 ch).
// No max-shift: w = exp(s) directly (|s| < ~20, safe in f32).
// Phase C (lane owns ch 2l,2l+1): w via 4x ds_read_b128 (wbuf[h][e] layout),
//   accumulate with v_fma_mix_f32.
// ---------------------------------------------------------------------------
#define XROW 136   // f16 stride per staged row

__global__ __launch_bounds__(256) void k_aggregate(
    const f16* __restrict__ xlh, const f16* __restrict__ xrh,
    const int* __restrict__ col, const int* __restrict__ cur,
    const int* __restrict__ bsum, const int* __restrict__ deg,
    const float* __restrict__ att, const float* __restrict__ bias,
    const float* __restrict__ gamma, const float* __restrict__ beta,
    float* __restrict__ out, int N)
{
    __shared__ f16   xbuf[4][16 * XROW];
    __shared__ float wbuf[4][64];
    __shared__ float lbuf[4][4];

    const int wid  = threadIdx.x >> 6;
    const int lane = threadIdx.x & 63;
    const int n    = blockIdx.x * 4 + wid;
    if (n >= N) return;

    const int end   = cur[n] + bsum[n >> 10];     // after fill: global end
    const int cnt   = deg[n] + 1;
    const int start = end - cnt;

    const int eB = lane >> 2;   // edge slot 0..15 (phase A/B)
    const int hB = lane & 3;    // head (phase A/B)
    const int hC = lane >> 4;   // head (phase C)

    // per-lane constants: xr & att slices for head hB (32 ch as 16 f16x2)
    f16x2 xr_s[16], at_s[16];
    {
        const uint4* xp = (const uint4*)(xrh + (size_t)n * CH + hB * 32);
#pragma unroll
        for (int q = 0; q < 4; ++q) {
            uint4 u = xp[q];
            xr_s[q * 4 + 0] = u2h(u.x); xr_s[q * 4 + 1] = u2h(u.y);
            xr_s[q * 4 + 2] = u2h(u.z); xr_s[q * 4 + 3] = u2h(u.w);
        }
        const float4* ap = (const float4*)(att + hB * 32);
#pragma unroll
        for (int j = 0; j < 8; ++j) {
            float4 a = ap[j];
            at_s[2 * j]     = (f16x2){(f16)a.x, (f16)a.y};
            at_s[2 * j + 1] = (f16x2){(f16)a.z, (f16)a.w};
        }
    }
    const f16x2 c02 = {(f16)NEG_SLOPE, (f16)NEG_SLOPE};

    float  l_run = 0.f;
    float2 acc   = make_float2(0.f, 0.f);

    for (int p0 = start; p0 < end; p0 += 16) {
        // ---- Phase A: gather + stage + packed-f16 score ----
        int pe = p0 + eB;
        int pc = pe < end ? pe : end - 1;
        int src = col[pc];
        const uint4* gp = (const uint4*)(xlh + (size_t)src * CH + hB * 32);
        uint4 q0 = gp[0], q1 = gp[1], q2 = gp[2], q3 = gp[3];

        f16* xw = &xbuf[wid][eB * XROW + hB * 32];
        *(uint4*)(xw)      = q0;
        *(uint4*)(xw + 8)  = q1;
        *(uint4*)(xw + 16) = q2;
        *(uint4*)(xw + 24) = q3;

        float s = 0.f;
        {
            uint4 qs[4] = {q0, q1, q2, q3};
#pragma unroll
            for (int q = 0; q < 4; ++q) {
                unsigned uu[4] = {qs[q].x, qs[q].y, qs[q].z, qs[q].w};
#pragma unroll
                for (int w = 0; w < 4; ++w) {
                    int idx = q * 4 + w;
                    f16x2 t  = u2h(uu[w]) + xr_s[idx];            // v_pk_add_f16
                    f16x2 lk = __builtin_elementwise_max(t, t * c02); // pk_mul+pk_max
                    s = __builtin_amdgcn_fdot2(lk, at_s[idx], s, false);
                }
            }
        }
        float w = (pe < end) ? __expf(s) : 0.f;

        // ---- Phase B: per-head denom accumulation (4 shuffles) ----
        float ws = w;
        ws += __shfl_xor(ws, 4);
        ws += __shfl_xor(ws, 8);
        ws += __shfl_xor(ws, 16);
        ws += __shfl_xor(ws, 32);
        l_run += ws;
        wbuf[wid][hB * 16 + eB] = w;              // transposed: [h][e]

        // ---- Phase C: weighted accumulate (fma_mix) ----
#pragma unroll
        for (int e = 0; e < 16; e += 4) {
            float4 w4 = *(const float4*)&wbuf[wid][hC * 16 + e];
            float wk[4] = {w4.x, w4.y, w4.z, w4.w};
#pragma unroll
            for (int k = 0; k < 4; ++k) {
                f16x2 hv = *(const f16x2*)&xbuf[wid][(e + k) * XROW + lane * 2];
                acc.x += (float)hv[0] * wk[k];    // v_fma_mix_f32
                acc.y += (float)hv[1] * wk[k];
            }
        }
    }

    if (lane < 4) lbuf[wid][lane] = l_run;        // lane = hB for lanes 0..3
    float l_c = lbuf[wid][hC];

    const int c = 2 * lane;
    const float inv = 1.f / l_c;
    float y0 = acc.x * inv + bias[c];
    float y1 = acc.y * inv + bias[c + 1];
    y0 = y0 / (1.f + __expf(-y0));   // SiLU
    y1 = y1 / (1.f + __expf(-y1));
    float s1 = y0 + y1;
    float s2 = y0 * y0 + y1 * y1;
#pragma unroll
    for (int off = 1; off < 64; off <<= 1) {
        s1 += __shfl_xor(s1, off);
        s2 += __shfl_xor(s2, off);
    }
    float mu   = s1 * (1.f / 128.f);
    float var  = s2 * (1.f / 128.f) - mu * mu;
    float rstd = rsqrtf(var + LN_EPS);
    float o0 = (y0 - mu) * rstd * gamma[c]     + beta[c];
    float o1 = (y1 - mu) * rstd * gamma[c + 1] + beta[c + 1];
    *(float2*)&out[(size_t)n * CH + c] = make_float2(o0, o1);
}

// ---------------------------------------------------------------------------
extern "C" void kernel_launch(void* const* d_in, const int* in_sizes, int n_in,
                              void* d_out, int out_size, void* d_ws, size_t ws_size,
                              hipStream_t stream)
{
    const float* x    = (const float*)d_in[0];
    const int*   ei   = (const int*)  d_in[1];
    const float* Wl   = (const float*)d_in[2];
    const float* bl   = (const float*)d_in[3];
    const float* Wr   = (const float*)d_in[4];
    const float* br   = (const float*)d_in[5];
    const float* att  = (const float*)d_in[6];
    const float* bias = (const float*)d_in[7];
    const float* gam  = (const float*)d_in[8];
    const float* bet  = (const float*)d_in[9];
    float* out = (float*)d_out;

    const int N  = in_sizes[0] / CH;      // 50000
    const int E  = in_sizes[1] / 2;       // 800000
    const int EN = E + N;

    char* ws = (char*)d_ws;
    size_t off = 0;
    auto carve = [&](size_t bytes) -> char* {
        char* p = ws + off;
        off += (bytes + 255) & ~(size_t)255;
        return p;
    };
    f16* xlh = (f16*)carve((size_t)N * CH * sizeof(f16));
    f16* xrh = (f16*)carve((size_t)N * CH * sizeof(f16));
    f16* Wt  = (f16*)carve((size_t)256 * CH * sizeof(f16));
    int* deg    = (int*)carve((size_t)N * sizeof(int));
    int* cur    = (int*)carve((size_t)N * sizeof(int));
    int* bsum   = (int*)carve(256 * sizeof(int));
    int* colidx = (int*)carve((size_t)EN * sizeof(int));
    (void)ws_size;

    const int nchunks = (N + 1023) / 1024;
    const int nwaves  = (N + 15) / 16;
    const int tblocks = (nwaves * 64 + 255) / 256;

    hipMemsetAsync(deg, 0, (size_t)N * sizeof(int), stream);
    k_prep_count<<<(E + 255) / 256, 256, 0, stream>>>(Wl, Wr, Wt, ei, E, deg);
    k_transform <<<tblocks, 256, 0, stream>>>(x, Wt, bl, br, xlh, xrh, N);
    k_scanA     <<<nchunks, 1024, 0, stream>>>(deg, cur, bsum, N);
    k_scanB     <<<1, 64, 0, stream>>>(bsum, nchunks);
    k_fill      <<<(EN + 255) / 256, 256, 0, stream>>>(ei, E, N, cur, bsum, colidx);
    k_aggregate <<<(N + 3) / 4, 256, 0, stream>>>(xlh, xrh, colidx, cur, bsum, deg,
                                                  att, bias, gam, bet, out, N);
}

// Round 5
// 268.321 us; speedup vs baseline: 1.3812x; 1.1374x over previous
//
#include <hip/hip_runtime.h>
#include <hip/hip_fp16.h>
#include <math.h>

#define CH 128          // IN_CH == OUT_CH == 128
#define NEG_SLOPE 0.2f
#define LN_EPS 1e-5f

typedef _Float16 f16;
typedef _Float16 f16x2 __attribute__((ext_vector_type(2)));
typedef _Float16 f16x8 __attribute__((ext_vector_type(8)));
typedef float    f32x4 __attribute__((ext_vector_type(4)));

__device__ __forceinline__ f16x2 u2h(unsigned u) {
    union { unsigned u; f16x2 h; } v; v.u = u; return v.h;
}

// all-reduce sum within each 16-lane row via DPP (no DS pipe, no waitcnt)
__device__ __forceinline__ float row16_allreduce(float x) {
    int t;
    t = __builtin_amdgcn_update_dpp(0, __builtin_bit_cast(int, x), 0xB1, 0xF, 0xF, false); // quad_perm(1,0,3,2)
    x += __builtin_bit_cast(float, t);
    t = __builtin_amdgcn_update_dpp(0, __builtin_bit_cast(int, x), 0x4E, 0xF, 0xF, false); // quad_perm(2,3,0,1)
    x += __builtin_bit_cast(float, t);
    t = __builtin_amdgcn_update_dpp(0, __builtin_bit_cast(int, x), 0x141, 0xF, 0xF, false); // row_half_mirror
    x += __builtin_bit_cast(float, t);
    t = __builtin_amdgcn_update_dpp(0, __builtin_bit_cast(int, x), 0x140, 0xF, 0xF, false); // row_mirror
    x += __builtin_bit_cast(float, t);
    return x;
}

// ---------------------------------------------------------------------------
// K1: Wt[col][k] = f16(col<128 ? Wl[k][col] : Wr[k][col-128]);
//     deg[dst]++ for all edges (deg pre-zeroed by memsetAsync).
// ---------------------------------------------------------------------------
__global__ void k_prep_count(const float* __restrict__ Wl, const float* __restrict__ Wr,
                             f16* __restrict__ Wt,
                             const int* __restrict__ ei, int E, int* __restrict__ deg)
{
    int tid = blockIdx.x * 256 + threadIdx.x;
    if (tid < 256 * CH) {
        int k   = tid >> 8;
        int col = tid & 255;
        float w = (col < CH) ? Wl[k * CH + col] : Wr[k * CH + (col - CH)];
        Wt[(size_t)col * CH + k] = (f16)w;
    }
    if (tid < E) atomicAdd(&deg[ei[E + tid]], 1);
}

// ---------------------------------------------------------------------------
// K2: MFMA f16 GEMM; wave computes 16 nodes x 256 cols (K=128).
// A = W columns (m=channel), B = x rows (n=node) => lane holds 4 consecutive
// channels of one node => packed 8B stores.
// ---------------------------------------------------------------------------
__global__ __launch_bounds__(256) void k_transform(
    const float* __restrict__ x, const f16* __restrict__ Wt,
    const float* __restrict__ bl, const float* __restrict__ br,
    f16* __restrict__ xlh, f16* __restrict__ xrh, int N)
{
    const int wave = (blockIdx.x * 256 + threadIdx.x) >> 6;
    const int lane = threadIdx.x & 63;
    const int m0   = wave * 16;
    if (m0 >= N) return;

    const int n16  = lane & 15;
    const int quad = lane >> 4;

    f16x8 xfr[4];
    {
        int mrow = m0 + n16; if (mrow >= N) mrow = N - 1;
        const float* xrow = x + (size_t)mrow * CH + quad * 8;
#pragma unroll
        for (int ks = 0; ks < 4; ++ks) {
            float4 p0 = *(const float4*)(xrow + ks * 32);
            float4 p1 = *(const float4*)(xrow + ks * 32 + 4);
            f16x8 f; f[0] = (f16)p0.x; f[1] = (f16)p0.y; f[2] = (f16)p0.z; f[3] = (f16)p0.w;
                     f[4] = (f16)p1.x; f[5] = (f16)p1.y; f[6] = (f16)p1.z; f[7] = (f16)p1.w;
            xfr[ks] = f;
        }
    }

#pragma unroll
    for (int ct = 0; ct < 16; ++ct) {
        f32x4 acc = {0.f, 0.f, 0.f, 0.f};
        const int acol = ct * 16 + n16;                       // A row = channel
        const f16* wp = Wt + (size_t)acol * CH + quad * 8;
#pragma unroll
        for (int ks = 0; ks < 4; ++ks) {
            f16x8 afr = *(const f16x8*)(wp + ks * 32);
            acc = __builtin_amdgcn_mfma_f32_16x16x32_f16(afr, xfr[ks], acc, 0, 0, 0);
        }
        const int node = m0 + n16;
        const int chq  = ct * 16 + quad * 4;
        if (node < N) {
            if (ct < 8) {
                float4 bv = *(const float4*)&bl[chq];
                f16x2 p0 = {(f16)(acc[0] + bv.x), (f16)(acc[1] + bv.y)};
                f16x2 p1 = {(f16)(acc[2] + bv.z), (f16)(acc[3] + bv.w)};
                f16* dst = xlh + (size_t)node * CH + chq;
                *(f16x2*)dst = p0; *(f16x2*)(dst + 2) = p1;
            } else {
                int cc = chq - CH;
                float4 bv = *(const float4*)&br[cc];
                f16x2 p0 = {(f16)(acc[0] + bv.x), (f16)(acc[1] + bv.y)};
                f16x2 p1 = {(f16)(acc[2] + bv.z), (f16)(acc[3] + bv.w)};
                f16* dst = xrh + (size_t)node * CH + cc;
                *(f16x2*)dst = p0; *(f16x2*)(dst + 2) = p1;
            }
        }
    }
}

// ---------------------------------------------------------------------------
// CSR: scanA (deg+1 -> local-exclusive cursor) -> scanB -> fill
// ---------------------------------------------------------------------------
__global__ __launch_bounds__(1024) void k_scanA(
    const int* __restrict__ deg, int* __restrict__ cur, int* __restrict__ bsum, int N)
{
    __shared__ int s[1024];
    const int tid = threadIdx.x;
    const int i   = blockIdx.x * 1024 + tid;
    const int d1  = (i < N) ? deg[i] + 1 : 0;     // +1 = self-loop
    s[tid] = d1;
    __syncthreads();
#pragma unroll
    for (int off = 1; off < 1024; off <<= 1) {
        int add = (tid >= off) ? s[tid - off] : 0;
        __syncthreads();
        s[tid] += add;
        __syncthreads();
    }
    if (i < N) cur[i] = s[tid] - d1;              // local exclusive
    if (tid == 1023) bsum[blockIdx.x] = s[1023];
}

__global__ void k_scanB(int* __restrict__ bsum, int nb, int* __restrict__ colpad)
{
    int lane = threadIdx.x;   // 64 threads, 1 block
    if (lane < 4) colpad[lane] = 0;   // zero the 4-int tail pad of colidx
    int carry = 0;
    for (int base = 0; base < nb; base += 64) {
        int i = base + lane;
        int v = (i < nb) ? bsum[i] : 0;
        int incl = v;
#pragma unroll
        for (int off = 1; off < 64; off <<= 1) {
            int t = __shfl_up(incl, off);
            if (lane >= off) incl += t;
        }
        if (i < nb) bsum[i] = carry + incl - v;   // exclusive
        carry += __shfl(incl, 63);
    }
}

__global__ void k_fill(const int* __restrict__ ei, int E, int N,
                       int* __restrict__ cur, const int* __restrict__ bsum,
                       int* __restrict__ col)
{
    int e = blockIdx.x * 256 + threadIdx.x;
    if (e < E) {
        int s = ei[e];
        int d = ei[E + e];
        int pos = atomicAdd(&cur[d], 1) + bsum[d >> 10];
        col[pos] = s;
    } else if (e < E + N) {
        int n = e - E;
        int pos = atomicAdd(&cur[n], 1) + bsum[n >> 10];
        col[pos] = n;
    }
}

// ---------------------------------------------------------------------------
// K6: aggregation + bias + SiLU + LayerNorm. One wave per node.
// lane owns channel pair (2l, 2l+1); head = lane>>4. Per edge:
//   gather f16x2 (whole 256B row coalesced across wave), score partial via
//   pk_add/pk_mul/pk_max/fdot2, 16-lane all-reduce via DPP (VALU only),
//   w = exp(s), acc += w*u (fma_mix). No LDS, no online max-shift.
// Edges processed in unrolled blocks of 4: 4 col loads + 4 gathers in flight.
// ---------------------------------------------------------------------------
__global__ __launch_bounds__(256) void k_aggregate(
    const f16* __restrict__ xlh, const f16* __restrict__ xrh,
    const int* __restrict__ col, const int* __restrict__ cur,
    const int* __restrict__ bsum, const int* __restrict__ deg,
    const float* __restrict__ att, const float* __restrict__ bias,
    const float* __restrict__ gamma, const float* __restrict__ beta,
    float* __restrict__ out, int N)
{
    const int wid  = threadIdx.x >> 6;
    const int lane = threadIdx.x & 63;
    const int n    = blockIdx.x * 4 + wid;
    if (n >= N) return;

    const int end   = cur[n] + bsum[n >> 10];
    const int cnt   = deg[n] + 1;
    const int start = end - cnt;

    const int c = 2 * lane;
    // per-lane constants
    f16x2 xr2, at2;
    {
        xr2 = *(const f16x2*)&xrh[(size_t)n * CH + c];
        float2 a = *(const float2*)&att[c];
        at2 = (f16x2){(f16)a.x, (f16)a.y};
    }
    const f16x2 c02 = {(f16)NEG_SLOPE, (f16)NEG_SLOPE};
    const unsigned lanehw = (unsigned)c;          // halfword offset in row

    float l_run = 0.f;
    float accx = 0.f, accy = 0.f;

    for (int p = start; p < end; p += 4) {
        // 4 uniform col loads + 4 row gathers issued together
        int c0 = col[p], c1 = col[p + 1], c2 = col[p + 2], c3 = col[p + 3];
        unsigned g0 = *(const unsigned*)(xlh + (((unsigned)c0) << 7) + lanehw);
        unsigned g1 = *(const unsigned*)(xlh + (((unsigned)c1) << 7) + lanehw);
        unsigned g2 = *(const unsigned*)(xlh + (((unsigned)c2) << 7) + lanehw);
        unsigned g3 = *(const unsigned*)(xlh + (((unsigned)c3) << 7) + lanehw);
        unsigned gs[4] = {g0, g1, g2, g3};
#pragma unroll
        for (int k = 0; k < 4; ++k) {
            f16x2 u  = u2h(gs[k]);
            f16x2 tt = u + xr2;                                   // v_pk_add_f16
            f16x2 lk = __builtin_elementwise_max(tt, tt * c02);   // leaky_relu
            float s  = __builtin_amdgcn_fdot2(lk, at2, 0.f, false);
            s = row16_allreduce(s);                               // head score
            float w = (p + k < end) ? __expf(s) : 0.f;
            l_run += w;
            accx += (float)u[0] * w;                              // v_fma_mix
            accy += (float)u[1] * w;
        }
    }

    const float inv = 1.f / l_run;    // l_run identical within head group
    float y0 = accx * inv + bias[c];
    float y1 = accy * inv + bias[c + 1];
    y0 = y0 / (1.f + __expf(-y0));    // SiLU
    y1 = y1 / (1.f + __expf(-y1));
    float s1 = y0 + y1;
    float s2 = y0 * y0 + y1 * y1;
#pragma unroll
    for (int off = 1; off < 64; off <<= 1) {
        s1 += __shfl_xor(s1, off);
        s2 += __shfl_xor(s2, off);
    }
    float mu   = s1 * (1.f / 128.f);
    float var  = s2 * (1.f / 128.f) - mu * mu;
    float rstd = rsqrtf(var + LN_EPS);
    float o0 = (y0 - mu) * rstd * gamma[c]     + beta[c];
    float o1 = (y1 - mu) * rstd * gamma[c + 1] + beta[c + 1];
    *(float2*)&out[(size_t)n * CH + c] = make_float2(o0, o1);
}

// ---------------------------------------------------------------------------
extern "C" void kernel_launch(void* const* d_in, const int* in_sizes, int n_in,
                              void* d_out, int out_size, void* d_ws, size_t ws_size,
                              hipStream_t stream)
{
    const float* x    = (const float*)d_in[0];
    const int*   ei   = (const int*)  d_in[1];
    const float* Wl   = (const float*)d_in[2];
    const float* bl   = (const float*)d_in[3];
    const float* Wr   = (const float*)d_in[4];
    const float* br   = (const float*)d_in[5];
    const float* att  = (const float*)d_in[6];
    const float* bias = (const float*)d_in[7];
    const float* gam  = (const float*)d_in[8];
    const float* bet  = (const float*)d_in[9];
    float* out = (float*)d_out;

    const int N  = in_sizes[0] / CH;      // 50000
    const int E  = in_sizes[1] / 2;       // 800000
    const int EN = E + N;

    char* ws = (char*)d_ws;
    size_t off = 0;
    auto carve = [&](size_t bytes) -> char* {
        char* p = ws + off;
        off += (bytes + 255) & ~(size_t)255;
        return p;
    };
    f16* xlh = (f16*)carve((size_t)N * CH * sizeof(f16));
    f16* xrh = (f16*)carve((size_t)N * CH * sizeof(f16));
    f16* Wt  = (f16*)carve((size_t)256 * CH * sizeof(f16));
    int* deg    = (int*)carve((size_t)N * sizeof(int));
    int* cur    = (int*)carve((size_t)N * sizeof(int));
    int* bsum   = (int*)carve(256 * sizeof(int));
    int* colidx = (int*)carve(((size_t)EN + 4) * sizeof(int));   // +4 pad for block overread
    (void)ws_size;

    const int nchunks = (N + 1023) / 1024;
    const int nwaves  = (N + 15) / 16;
    const int tblocks = (nwaves * 64 + 255) / 256;

    hipMemsetAsync(deg, 0, (size_t)N * sizeof(int), stream);
    k_prep_count<<<(E + 255) / 256, 256, 0, stream>>>(Wl, Wr, Wt, ei, E, deg);
    k_transform <<<tblocks, 256, 0, stream>>>(x, Wt, bl, br, xlh, xrh, N);
    k_scanA     <<<nchunks, 1024, 0, stream>>>(deg, cur, bsum, N);
    k_scanB     <<<1, 64, 0, stream>>>(bsum, nchunks, colidx + EN);
    k_fill      <<<(EN + 255) / 256, 256, 0, stream>>>(ei, E, N, cur, bsum, colidx);
    k_aggregate <<<(N + 3) / 4, 256, 0, stream>>>(xlh, xrh, colidx, cur, bsum, deg,
                                                  att, bias, gam, bet, out, N);
}